// Round 3
// baseline (793.395 us; speedup 1.0000x reference)
//
#include <hip/hip_runtime.h>

#define Bsz 512
#define Ssz 512
#define Isz 32
#define Hsz 128
#define BB  2
#define LOG2E 1.44269504088896340736f

typedef __attribute__((ext_vector_type(8))) short bf16x8;
typedef __attribute__((ext_vector_type(4))) float f32x4;

__device__ __forceinline__ unsigned short f2bf(float f){
  unsigned u = __float_as_uint(f);
  return (unsigned short)((u + 0x7FFFu + ((u >> 16) & 1u)) >> 16);
}
__device__ __forceinline__ float sigm_p(float xp){          // pre-scaled by log2e
  return __builtin_amdgcn_rcpf(1.f + __builtin_amdgcn_exp2f(-xp));
}
__device__ __forceinline__ float tanh_p(float xp2){         // pre-scaled by 2*log2e
  return 1.f - 2.f * __builtin_amdgcn_rcpf(1.f + __builtin_amdgcn_exp2f(xp2));
}
__device__ __forceinline__ bf16x8 ldw(const float* p, float s){
  bf16x8 r;
#pragma unroll
  for (int e=0;e<8;++e) r[e] = (short)f2bf(p[e]*s);
  return r;
}
__device__ __forceinline__ bf16x8 ldws(const float* pa, const float* pb, float s){
  bf16x8 r;
#pragma unroll
  for (int e=0;e<8;++e) r[e] = (short)f2bf((pa[e]+pb[e])*s);
  return r;
}

__global__ __launch_bounds__(256, 1) void lstm_ae(
    const float* __restrict__ x,
    const float* __restrict__ eWih, const float* __restrict__ eWhh,
    const float* __restrict__ ebih, const float* __restrict__ ebhh,
    const float* __restrict__ dWih, const float* __restrict__ dWhh,
    const float* __restrict__ dbih, const float* __restrict__ dbhh,
    const float* __restrict__ fcW,  const float* __restrict__ fcb,
    float* __restrict__ out)
{
  __shared__ __attribute__((aligned(16))) float big[2*Ssz*Isz];     // x bf16 / frames f32
  __shared__ __attribute__((aligned(16))) float sc[4*4*64];         // intra-wave gate scratch
  __shared__ __attribute__((aligned(16))) unsigned short hbuf[2][2][Hsz];

  const int tid  = threadIdx.x;
  const int lane = tid & 63;
  const int wv   = tid >> 6;
  const int c16  = lane & 15;
  const int quad = lane >> 4;
  const int bg0  = blockIdx.x * BB;

  const int ab = lane >> 5;            // act: batch row
  const int kl = lane & 31;            // act: col within wave slice
  const int ak = wv*32 + kl;           // act: h col 0..127
  const int hrow = c16 & 1;            // A-frag row (rows>=2 duplicate, harmless)

  // ---- stage x as bf16 into LDS ----
  unsigned short* xl = (unsigned short*)big;
#pragma unroll 4
  for (int i = tid*4; i < 2*Ssz*Isz; i += 256*4){
    f32x4 v = *(const f32x4*)(x + (size_t)(bg0 + (i>>14))*(Ssz*Isz) + (i & 16383));
    xl[i+0]=f2bf(v[0]); xl[i+1]=f2bf(v[1]); xl[i+2]=f2bf(v[2]); xl[i+3]=f2bf(v[3]);
  }
  ((unsigned short*)hbuf)[tid]     = 0;
  ((unsigned short*)hbuf)[tid+256] = 0;

  // K-chunk permutation: slot m handles global chunk (wv+m)&3; slot 0 = own cols
  int co[4];
#pragma unroll
  for (int m=0;m<4;++m) co[m] = ((wv+m)&3)*32 + quad*8;   // shorts

  // ---- encoder weights (pre-permuted by slot) ----
  bf16x8 W[8][4], wx[8];
#pragma unroll
  for (int j=0;j<8;++j){
    int g = j>>1;
    int n = g*128 + wv*32 + (j&1)*16 + c16;
    float s = (g==2) ? 2.f*LOG2E : LOG2E;
#pragma unroll
    for (int m=0;m<4;++m)
      W[j][m] = ldw(eWhh + (size_t)n*Hsz + ((wv+m)&3)*32 + quad*8, s);
    wx[j] = ldw(eWih + (size_t)n*Isz + quad*8, s);
  }
  float b_i = (ebih[0*Hsz+ak]+ebhh[0*Hsz+ak])*LOG2E;
  float b_f = (ebih[1*Hsz+ak]+ebhh[1*Hsz+ak])*LOG2E;
  float b_g = (ebih[2*Hsz+ak]+ebhh[2*Hsz+ak])*(2.f*LOG2E);
  float b_o = (ebih[3*Hsz+ak]+ebhh[3*Hsz+ak])*LOG2E;

  const f32x4 zero4 = {0.f,0.f,0.f,0.f};
  float cst = 0.f;
  const unsigned short* hb = &hbuf[0][0][0];

  auto scatter = [&](f32x4* acc){
    if (quad == 0){
      float* s0 = sc + wv*256 + c16;
#pragma unroll
      for (int j=0;j<8;++j){
        float* p = s0 + (j>>1)*64 + (j&1)*16;
        p[0]  = acc[j][0];
        p[32] = acc[j][1];
      }
    }
  };
  auto act = [&](int wp, bool upd){
    const float* s0 = sc + wv*256 + lane;
    float pi = s0[0]   + b_i;
    float pf = s0[64]  + b_f;
    float pg = s0[128] + b_g;
    float po = s0[192] + b_o;
    float iv = sigm_p(pi), fv = sigm_p(pf), ov = sigm_p(po);
    float gv = tanh_p(pg);
    float cn = fv*cst + iv*gv;
    if (upd) cst = cn;
    float hh = ov * tanh_p(cn*(2.f*LOG2E));
    hbuf[wp][ab][ak] = f2bf(hh);
  };

  __syncthreads();

  // ---------------- encoder ----------------
  int par = 0;
  bf16x8 ax = *(const bf16x8*)(xl + hrow*(Ssz*Isz) + quad*8);   // t=0
  for (int t=0; t<Ssz; ++t){
    const unsigned short* hp = hb + par*256 + hrow*128;
    bf16x8 ah0 = *(const bf16x8*)(hp + co[0]);
    f32x4 acc[8];
#pragma unroll
    for (int j=0;j<8;++j) acc[j] = __builtin_amdgcn_mfma_f32_16x16x32_bf16(ax, wx[j], zero4, 0,0,0);
#pragma unroll
    for (int j=0;j<8;++j) acc[j] = __builtin_amdgcn_mfma_f32_16x16x32_bf16(ah0, W[j][0], acc[j], 0,0,0);
    __syncthreads();
    bf16x8 ah1 = *(const bf16x8*)(hp + co[1]);
    bf16x8 ah2 = *(const bf16x8*)(hp + co[2]);
    bf16x8 ah3 = *(const bf16x8*)(hp + co[3]);
    int tn = (t+1 < Ssz) ? t+1 : 0;
    ax = *(const bf16x8*)(xl + hrow*(Ssz*Isz) + tn*Isz + quad*8);
#pragma unroll
    for (int j=0;j<8;++j) acc[j] = __builtin_amdgcn_mfma_f32_16x16x32_bf16(ah1, W[j][1], acc[j], 0,0,0);
#pragma unroll
    for (int j=0;j<8;++j) acc[j] = __builtin_amdgcn_mfma_f32_16x16x32_bf16(ah2, W[j][2], acc[j], 0,0,0);
#pragma unroll
    for (int j=0;j<8;++j) acc[j] = __builtin_amdgcn_mfma_f32_16x16x32_bf16(ah3, W[j][3], acc[j], 0,0,0);
    scatter(acc);
    act(par^1, true);
    par ^= 1;
  }

  // ---------------- decoder ----------------
  b_i = (dbih[0*Hsz+ak]+dbhh[0*Hsz+ak])*LOG2E;
  b_f = (dbih[1*Hsz+ak]+dbhh[1*Hsz+ak])*LOG2E;
  b_g = (dbih[2*Hsz+ak]+dbhh[2*Hsz+ak])*(2.f*LOG2E);
  b_o = (dbih[3*Hsz+ak]+dbhh[3*Hsz+ak])*LOG2E;

  // step 0: gates = enc_h @ dWhh^T + b   (cell stays enc_c)
#pragma unroll
  for (int j=0;j<8;++j){
    int g = j>>1;
    int n = g*128 + wv*32 + (j&1)*16 + c16;
    float s = (g==2) ? 2.f*LOG2E : LOG2E;
#pragma unroll
    for (int m=0;m<4;++m)
      W[j][m] = ldw(dWhh + (size_t)n*Hsz + ((wv+m)&3)*32 + quad*8, s);
  }
  {
    const unsigned short* hp = hb + par*256 + hrow*128;
    bf16x8 ah0 = *(const bf16x8*)(hp + co[0]);
    f32x4 acc[8];
#pragma unroll
    for (int j=0;j<8;++j) acc[j] = __builtin_amdgcn_mfma_f32_16x16x32_bf16(ah0, W[j][0], zero4, 0,0,0);
    __syncthreads();
    bf16x8 ah1 = *(const bf16x8*)(hp + co[1]);
    bf16x8 ah2 = *(const bf16x8*)(hp + co[2]);
    bf16x8 ah3 = *(const bf16x8*)(hp + co[3]);
#pragma unroll
    for (int j=0;j<8;++j) acc[j] = __builtin_amdgcn_mfma_f32_16x16x32_bf16(ah1, W[j][1], acc[j], 0,0,0);
#pragma unroll
    for (int j=0;j<8;++j) acc[j] = __builtin_amdgcn_mfma_f32_16x16x32_bf16(ah2, W[j][2], acc[j], 0,0,0);
#pragma unroll
    for (int j=0;j<8;++j) acc[j] = __builtin_amdgcn_mfma_f32_16x16x32_bf16(ah3, W[j][3], acc[j], 0,0,0);
    scatter(acc);
    act(par^1, false);
    par ^= 1;
  }

  // steps >=1: inp == h -> W = (dWih + dWhh), plus fc on waves 0,1
#pragma unroll
  for (int j=0;j<8;++j){
    int g = j>>1;
    int n = g*128 + wv*32 + (j&1)*16 + c16;
    float s = (g==2) ? 2.f*LOG2E : LOG2E;
#pragma unroll
    for (int m=0;m<4;++m){
      int ko = ((wv+m)&3)*32 + quad*8;
      W[j][m] = ldws(dWih + (size_t)n*Hsz + ko, dWhh + (size_t)n*Hsz + ko, s);
    }
  }
  bf16x8 wf[4];
  f32x4 biasf4 = {0.f,0.f,0.f,0.f};
  if (wv < 2){
    int n = wv*16 + c16;
#pragma unroll
    for (int m=0;m<4;++m)
      wf[m] = ldw(fcW + (size_t)n*Hsz + ((wv+m)&3)*32 + quad*8, 1.f);
    float bf = fcb[n];
    biasf4[0]=bf; biasf4[1]=bf; biasf4[2]=bf; biasf4[3]=bf;
  }
  float* fr = big;

  for (int t=1; t<Ssz; ++t){
    const unsigned short* hp = hb + par*256 + hrow*128;
    bf16x8 ah0 = *(const bf16x8*)(hp + co[0]);
    f32x4 acc[8];
    f32x4 fa;
#pragma unroll
    for (int j=0;j<8;++j) acc[j] = __builtin_amdgcn_mfma_f32_16x16x32_bf16(ah0, W[j][0], zero4, 0,0,0);
    if (wv < 2) fa = __builtin_amdgcn_mfma_f32_16x16x32_bf16(ah0, wf[0], biasf4, 0,0,0);
    __syncthreads();
    bf16x8 ah1 = *(const bf16x8*)(hp + co[1]);
    bf16x8 ah2 = *(const bf16x8*)(hp + co[2]);
    bf16x8 ah3 = *(const bf16x8*)(hp + co[3]);
#pragma unroll
    for (int j=0;j<8;++j) acc[j] = __builtin_amdgcn_mfma_f32_16x16x32_bf16(ah1, W[j][1], acc[j], 0,0,0);
    if (wv < 2) fa = __builtin_amdgcn_mfma_f32_16x16x32_bf16(ah1, wf[1], fa, 0,0,0);
#pragma unroll
    for (int j=0;j<8;++j) acc[j] = __builtin_amdgcn_mfma_f32_16x16x32_bf16(ah2, W[j][2], acc[j], 0,0,0);
    if (wv < 2) fa = __builtin_amdgcn_mfma_f32_16x16x32_bf16(ah2, wf[2], fa, 0,0,0);
#pragma unroll
    for (int j=0;j<8;++j) acc[j] = __builtin_amdgcn_mfma_f32_16x16x32_bf16(ah3, W[j][3], acc[j], 0,0,0);
    if (wv < 2){
      fa = __builtin_amdgcn_mfma_f32_16x16x32_bf16(ah3, wf[3], fa, 0,0,0);
      if (quad == 0){
        fr[          (t-1)*Isz + wv*16 + c16] = fa[0];
        fr[Ssz*Isz + (t-1)*Isz + wv*16 + c16] = fa[1];
      }
    }
    scatter(acc);
    act(par^1, false);
    par ^= 1;
  }

  // epilogue: frame s=511
  __syncthreads();
  {
    const unsigned short* hp = hb + par*256 + hrow*128;
    if (wv < 2){
      bf16x8 ah0 = *(const bf16x8*)(hp + co[0]);
      bf16x8 ah1 = *(const bf16x8*)(hp + co[1]);
      bf16x8 ah2 = *(const bf16x8*)(hp + co[2]);
      bf16x8 ah3 = *(const bf16x8*)(hp + co[3]);
      f32x4 fa = __builtin_amdgcn_mfma_f32_16x16x32_bf16(ah0, wf[0], biasf4, 0,0,0);
      fa = __builtin_amdgcn_mfma_f32_16x16x32_bf16(ah1, wf[1], fa, 0,0,0);
      fa = __builtin_amdgcn_mfma_f32_16x16x32_bf16(ah2, wf[2], fa, 0,0,0);
      fa = __builtin_amdgcn_mfma_f32_16x16x32_bf16(ah3, wf[3], fa, 0,0,0);
      if (quad == 0){
        fr[          (Ssz-1)*Isz + wv*16 + c16] = fa[0];
        fr[Ssz*Isz + (Ssz-1)*Isz + wv*16 + c16] = fa[1];
      }
    }
  }
  __syncthreads();

#pragma unroll 4
  for (int i = tid*4; i < 2*Ssz*Isz; i += 256*4){
    f32x4 v = *(const f32x4*)(big + i);
    *(f32x4*)(out + (size_t)(bg0 + (i>>14))*(Ssz*Isz) + (i & 16383)) = v;
  }
}

extern "C" void kernel_launch(void* const* d_in, const int* in_sizes, int n_in,
                              void* d_out, int out_size, void* d_ws, size_t ws_size,
                              hipStream_t stream) {
  const float* x    = (const float*)d_in[0];
  const float* eWih = (const float*)d_in[1];
  const float* eWhh = (const float*)d_in[2];
  const float* ebih = (const float*)d_in[3];
  const float* ebhh = (const float*)d_in[4];
  const float* dWih = (const float*)d_in[5];
  const float* dWhh = (const float*)d_in[6];
  const float* dbih = (const float*)d_in[7];
  const float* dbhh = (const float*)d_in[8];
  const float* fcW  = (const float*)d_in[9];
  const float* fcb  = (const float*)d_in[10];
  float* outp = (float*)d_out;
  (void)d_ws; (void)ws_size; (void)in_sizes; (void)n_in; (void)out_size;
  lstm_ae<<<dim3(Bsz/BB), dim3(256), 0, stream>>>(
      x, eWih, eWhh, ebih, ebhh, dWih, dWhh, dbih, dbhh, fcW, fcb, outp);
}